// Round 3
// baseline (1533.505 us; speedup 1.0000x reference)
//
#include <hip/hip_runtime.h>
#include <hip/hip_bf16.h>
#include <cstdint>

// B=4, S=4096, E=2048, H=16, D=128 -> 16384 independent tokens.
// qkv = x @ W_qkv (16384x2048x6144); per-token 16x16 head mix;
// out = attn @ W_out + b_out (16384x2048x2048).

#define TOKENS 16384
#define EMB    2048
#define NQKV   6144

typedef __bf16 bf16x8_t __attribute__((ext_vector_type(8)));
typedef float  f32x4_t  __attribute__((ext_vector_type(4)));

#define GLOAD16(gsrc, ldst)                                                    \
  __builtin_amdgcn_global_load_lds(                                            \
      (const __attribute__((address_space(1))) void*)(uintptr_t)(gsrc),        \
      (__attribute__((address_space(3))) void*)(uint32_t)(uintptr_t)(ldst),    \
      16, 0, 0)

static __device__ __forceinline__ unsigned short f32_to_bf16_bits(float f) {
  union { float f; uint32_t u; } x; x.f = f;
  uint32_t u = x.u;
  u += 0x7fffu + ((u >> 16) & 1u);   // round-to-nearest-even
  return (unsigned short)(u >> 16);
}

// ---------------------------------------------------------------- converts
__global__ __launch_bounds__(256) void cvt_f32_bf16(
    const float4* __restrict__ in, ushort4* __restrict__ out, int n4) {
  const int stride = gridDim.x * blockDim.x;
  for (int i = blockIdx.x * blockDim.x + threadIdx.x; i < n4; i += stride) {
    float4 v = in[i];
    ushort4 o;
    o.x = f32_to_bf16_bits(v.x);
    o.y = f32_to_bf16_bits(v.y);
    o.z = f32_to_bf16_bits(v.z);
    o.w = f32_to_bf16_bits(v.w);
    out[i] = o;
  }
}

// transpose R x C f32 -> C x R bf16
__global__ __launch_bounds__(256) void transpose_cvt(
    const float* __restrict__ in, unsigned short* __restrict__ out, int R, int C) {
  __shared__ float tile[32][33];
  const int bx = blockIdx.x * 32;
  const int by = blockIdx.y * 32;
  const int tx = threadIdx.x;
  const int ty = threadIdx.y;
#pragma unroll
  for (int j = 0; j < 32; j += 8)
    tile[ty + j][tx] = in[(size_t)(by + ty + j) * C + bx + tx];
  __syncthreads();
#pragma unroll
  for (int j = 0; j < 32; j += 8)
    out[(size_t)(bx + ty + j) * R + by + tx] = f32_to_bf16_bits(tile[tx][ty + j]);
}

// ---------------------------------------------------------------- GEMM
// 256x256 tile, BK=64, 8 waves (2M x 4N). Skewed 4-phase schedule:
// each phase issues the NEXT phase's ds_reads (compiler emits counted
// lgkmcnt), so LDS drain hides under MFMA. One counted vmcnt(4)/K-tile.
template <bool OUT_BF16>
__global__ __launch_bounds__(512, 1) void gemm_bt(
    const unsigned short* __restrict__ A,
    const unsigned short* __restrict__ BT,
    unsigned short* __restrict__ Cb,
    float* __restrict__ Cf,
    const float* __restrict__ bias,
    int M, int N) {
  constexpr int K = 2048;
  constexpr int BK = 64;
  constexpr int NKT = K / BK;          // 32 (even)
  __shared__ __align__(16) char lds[131072];  // [2 bufs][A 32KB | B 32KB]

  const int nbx = N / 256;
  const int nwg = gridDim.x;           // % 8 == 0
  const int bid = blockIdx.x;
  const int swzb = (bid & 7) * (nwg >> 3) + (bid >> 3);
  const int by = swzb / nbx;
  const int bx = swzb % nbx;

  const int t    = threadIdx.x;
  const int lane = t & 63;
  const int wid  = t >> 6;             // 0..7
  const int wr   = wid >> 2;           // 0..1 (M)
  const int wc   = wid & 3;            // 0..3 (N)
  const int lr   = lane & 15;
  const int g    = lane >> 4;          // 0..3

  const unsigned short* aSrc = A  + (size_t)by * 256 * K;
  const unsigned short* bSrc = BT + (size_t)bx * 256 * K;

  // staging source offsets (inverse-swizzled global, linear LDS dest)
  int aoff[2], boff[2];
#pragma unroll
  for (int i = 0; i < 2; ++i) {
    const int p   = (i * 512 + t) * 16;
    const int lo  = p ^ (((p >> 7) & 7) << 4);
    const int rih = lo >> 7;
    const int kbe = (lo & 127) >> 1;
    aoff[i] = (((rih >> 6) << 7) + (rih & 63)) * K + kbe;
    boff[i] = (((rih >> 5) << 6) + (rih & 31)) * K + kbe;
  }
  const int ldst = wid << 10;

  auto stageA = [&](int h, int k0, char* bufA) {
#pragma unroll
    for (int i = 0; i < 2; ++i)
      GLOAD16(aSrc + aoff[i] + h * (64 * K) + k0, bufA + h * 16384 + i * 8192 + ldst);
  };
  auto stageB = [&](int h, int k0, char* bufB) {
#pragma unroll
    for (int i = 0; i < 2; ++i)
      GLOAD16(bSrc + boff[i] + h * (32 * K) + k0, bufB + h * 16384 + i * 8192 + ldst);
  };

  // swizzled ds_read addresses
  const int sw   = (lr & 7) << 4;
  const int col0 = (g * 16) ^ sw;
  const int col1 = (64 + g * 16) ^ sw;
  const int aRow = (wr * 64 + lr) * 128;
  const int bRow = (wc * 32 + lr) * 128;

  f32x4_t acc[8][4] = {};
  bf16x8_t av0[4][2], av1[4][2];       // A quadrant frags [m2][ks]
  bf16x8_t bv1[2][2];                  // B pair1 [e][ks]
  bf16x8_t bv0A[2][2], bv0B[2][2];     // B pair0, ping-pong

#define LDA_INTO(dst, bufA_, q)                                                \
  {                                                                            \
    const char* _b = (bufA_) + (q) * 16384 + aRow;                             \
    _Pragma("unroll") for (int m2 = 0; m2 < 4; ++m2) {                         \
      dst[m2][0] = *(const bf16x8_t*)(_b + m2 * 2048 + col0);                  \
      dst[m2][1] = *(const bf16x8_t*)(_b + m2 * 2048 + col1);                  \
    }                                                                          \
  }
#define LDB_INTO(dst, bufB_, pair)                                             \
  {                                                                            \
    _Pragma("unroll") for (int e = 0; e < 2; ++e) {                            \
      const int nf = (pair) * 2 + e;                                           \
      const char* _b = (bufB_) + (nf >> 1) * 16384 + (nf & 1) * 2048 + bRow;   \
      dst[e][0] = *(const bf16x8_t*)(_b + col0);                               \
      dst[e][1] = *(const bf16x8_t*)(_b + col1);                               \
    }                                                                          \
  }
#define MFMAQ(AV, BV, Q, PAIR)                                                 \
  _Pragma("unroll") for (int m2 = 0; m2 < 4; ++m2)                             \
  _Pragma("unroll") for (int e = 0; e < 2; ++e)                                \
  _Pragma("unroll") for (int ks = 0; ks < 2; ++ks)                             \
    acc[(Q) * 4 + m2][(PAIR) * 2 + e] = __builtin_amdgcn_mfma_f32_16x16x32_bf16( \
        AV[m2][ks], BV[e][ks], acc[(Q) * 4 + m2][(PAIR) * 2 + e], 0, 0, 0);

#define SBR __builtin_amdgcn_sched_barrier(0)
#define PHASE_MID                                                              \
  SBR; __builtin_amdgcn_s_barrier(); SBR; __builtin_amdgcn_s_setprio(1);
#define PHASE_END                                                              \
  __builtin_amdgcn_s_setprio(0); SBR; __builtin_amdgcn_s_barrier();

  // One sub-iteration (4 skewed phases). BVC = pair0 set consumed this tile,
  // BVN = pair0 set loaded for the next tile. CU = this tile's buffer index.
#define SUBITER(KT, BVC, BVN, CU)                                              \
  {                                                                            \
    char* curA = lds + (CU) * 65536;                                           \
    char* curB = curA + 32768;                                                 \
    char* nxtA = lds + ((CU) ^ 1) * 65536;                                     \
    char* nxtB = nxtA + 32768;                                                 \
    const int k2  = ((KT) + 2) * BK;                                           \
    const bool s1 = (KT) + 1 < NKT;                                            \
    const bool s2 = (KT) + 2 < NKT;                                            \
    /* P1: read Bn1(cur); mfma (q0, p0) */                                     \
    LDB_INTO(bv1, curB, 1);                                                    \
    PHASE_MID; MFMAQ(av0, BVC, 0, 0); PHASE_END;                               \
    /* P2: read A q1(cur); stage B(kt+2)->curB; mfma (q0, p1) */               \
    LDA_INTO(av1, curA, 1);                                                    \
    if (s2) { stageB(0, k2, curB); stageB(1, k2, curB); }                      \
    PHASE_MID; MFMAQ(av0, bv1, 0, 1); PHASE_END;                               \
    /* P3: vmcnt; read next q0; stage Ah0(kt+2)->curA; mfma (q1, p1) */        \
    if (s1) {                                                                  \
      if (s2) { asm volatile("s_waitcnt vmcnt(4)" ::: "memory"); }             \
      else    { asm volatile("s_waitcnt vmcnt(0)" ::: "memory"); }             \
      LDA_INTO(av0, nxtA, 0);                                                  \
    }                                                                          \
    if (s2) stageA(0, k2, curA);                                               \
    PHASE_MID; MFMAQ(av1, bv1, 1, 1); PHASE_END;                               \
    /* P4: read next p0 -> BVN; stage Ah1(kt+2)->curA; mfma (q1, p0) */        \
    if (s1) LDB_INTO(BVN, nxtB, 0);                                            \
    if (s2) stageA(1, k2, curA);                                               \
    PHASE_MID; MFMAQ(av1, BVC, 1, 0); PHASE_END;                               \
  }

  // prologue: tile0 -> buf0, tile1 -> buf1; first reads for P1 of kt=0
  {
    char* b0A = lds;
    char* b0B = lds + 32768;
    char* b1A = lds + 65536;
    char* b1B = b1A + 32768;
    stageA(0, 0, b0A); stageA(1, 0, b0A);
    stageB(0, 0, b0B); stageB(1, 0, b0B);
    stageA(0, BK, b1A); stageA(1, BK, b1A);
    stageB(0, BK, b1B); stageB(1, BK, b1B);
    asm volatile("s_waitcnt vmcnt(8)" ::: "memory");  // tile 0 landed
    __builtin_amdgcn_s_barrier();
    LDA_INTO(av0, b0A, 0);
    LDB_INTO(bv0A, b0B, 0);
  }

  for (int kt = 0; kt < NKT; kt += 2) {
    SUBITER(kt,     bv0A, bv0B, 0);
    SUBITER(kt + 1, bv0B, bv0A, 1);
  }

  // epilogue: C/D map col=lane&15, row=(lane>>4)*4+j
  const int rbase = by * 256 + wr * 128 + g * 4;
  const int cbase = bx * 256 + wc * 64 + lr;
#pragma unroll
  for (int m = 0; m < 8; ++m) {
#pragma unroll
    for (int nf = 0; nf < 4; ++nf) {
      const int col = cbase + nf * 16;
#pragma unroll
      for (int j = 0; j < 4; ++j) {
        const size_t off = (size_t)(rbase + (m >> 2) * 64 + (m & 3) * 16 + j) * N + col;
        if constexpr (OUT_BF16) {
          Cb[off] = f32_to_bf16_bits(acc[m][nf][j]);
        } else {
          Cf[off] = acc[m][nf][j] + bias[col];
        }
      }
    }
  }
#undef LDA_INTO
#undef LDB_INTO
#undef MFMAQ
#undef SBR
#undef PHASE_MID
#undef PHASE_END
#undef SUBITER
}

// ---------------------------------------------------------------- attention
__global__ __launch_bounds__(256) void attn_heads(
    const unsigned short* __restrict__ qkv,  // [T][6144] bf16
    unsigned short* __restrict__ attn) {     // [T][2048] bf16
  __shared__ __align__(16) unsigned short sQKV[NQKV];
  __shared__ float sW[16][16];

  const int t = threadIdx.x;
  const size_t qbase = (size_t)blockIdx.x * NQKV;

  const uint4* gp = (const uint4*)(qkv + qbase);
  uint4* l = (uint4*)sQKV;
#pragma unroll
  for (int i = 0; i < 3; ++i) {
    const int idx = i * 256 + t;
    int dst = idx;
    if (idx >= 256 && idx < 512) {
      const int r = (idx - 256) >> 4;
      const int c = idx & 15;
      dst = 256 + r * 16 + (c ^ (r & 7));
    }
    l[dst] = gp[idx];
  }
  __syncthreads();

  const int h = t >> 4;
  const int H = t & 15;
  const bf16x8_t* q8 = (const bf16x8_t*)sQKV + h * 16;
  const bf16x8_t* k8 = (const bf16x8_t*)sQKV + 256;
  float s = 0.f;
#pragma unroll
  for (int d8 = 0; d8 < 16; ++d8) {
    bf16x8_t qv = q8[d8];
    bf16x8_t kv = k8[H * 16 + (d8 ^ (H & 7))];
#pragma unroll
    for (int j = 0; j < 8; ++j)
      s = fmaf((float)qv[j], (float)kv[j], s);
  }
  s *= 0.08838834764831843f;

  float mx = s;
#pragma unroll
  for (int o = 8; o; o >>= 1) mx = fmaxf(mx, __shfl_xor(mx, o));
  const float e = __expf(s - mx);
  float sum = e;
#pragma unroll
  for (int o = 8; o; o >>= 1) sum += __shfl_xor(sum, o);
  sW[h][H] = e / sum;
  __syncthreads();

  const int d0c = t & 15;
  const bf16x8_t* v8 = (const bf16x8_t*)sQKV + 512;
  float accv[8] = {};
#pragma unroll
  for (int j = 0; j < 16; ++j) {
    const float w = sW[h][j];
    const bf16x8_t vv = v8[j * 16 + d0c];
#pragma unroll
    for (int jj = 0; jj < 8; ++jj)
      accv[jj] = fmaf(w, (float)vv[jj], accv[jj]);
  }
  bf16x8_t o;
#pragma unroll
  for (int jj = 0; jj < 8; ++jj) o[jj] = (__bf16)accv[jj];
  *(bf16x8_t*)(attn + (size_t)blockIdx.x * EMB + h * 128 + d0c * 8) = o;
}

// ---------------------------------------------------------------- launch
extern "C" void kernel_launch(void* const* d_in, const int* in_sizes, int n_in,
                              void* d_out, int out_size, void* d_ws, size_t ws_size,
                              hipStream_t stream) {
  const float* x    = (const float*)d_in[0];
  const float* Wqkv = (const float*)d_in[1];
  const float* Wout = (const float*)d_in[2];
  const float* bout = (const float*)d_in[3];
  float* out = (float*)d_out;

  unsigned short* xb    = (unsigned short*)d_ws;          // 33,554,432
  unsigned short* wqkvT = xb    + (size_t)33554432;       // 12,582,912
  unsigned short* woutT = wqkvT + (size_t)12582912;       //  4,194,304
  unsigned short* qkv   = woutT + (size_t)4194304;        // 100,663,296
  unsigned short* attn  = qkv   + (size_t)100663296;      // 33,554,432

  cvt_f32_bf16<<<2048, 256, 0, stream>>>((const float4*)x, (ushort4*)xb, 33554432 / 4);
  transpose_cvt<<<dim3(6144 / 32, 2048 / 32), dim3(32, 8), 0, stream>>>(Wqkv, wqkvT, 2048, 6144);
  transpose_cvt<<<dim3(2048 / 32, 2048 / 32), dim3(32, 8), 0, stream>>>(Wout, woutT, 2048, 2048);
  // qkv = x @ W_qkv : grid 64*24 = 1536 (%8==0)
  gemm_bt<true><<<(16384 / 256) * (6144 / 256), 512, 0, stream>>>(
      xb, wqkvT, qkv, nullptr, nullptr, 16384, 6144);
  attn_heads<<<TOKENS, 256, 0, stream>>>(qkv, attn);
  // out = attn @ W_out + b_out : grid 64*8 = 512 (%8==0)
  gemm_bt<false><<<(16384 / 256) * (2048 / 256), 512, 0, stream>>>(
      attn, woutT, nullptr, out, bout, 16384, 2048);
}

// Round 4
// 637.771 us; speedup vs baseline: 2.4045x; 2.4045x over previous
//
#include <hip/hip_runtime.h>
#include <hip/hip_bf16.h>
#include <cstdint>

// B=4, S=4096, E=2048, H=16, D=128 -> 16384 independent tokens.
// qkv = x @ W_qkv (16384x2048x6144); per-token 16x16 head mix;
// out = attn @ W_out + b_out (16384x2048x2048).

#define TOKENS 16384
#define EMB    2048
#define NQKV   6144

typedef __bf16 bf16x8_t __attribute__((ext_vector_type(8)));
typedef float  f32x4_t  __attribute__((ext_vector_type(4)));

#define GLOAD16(gsrc, ldst)                                                    \
  __builtin_amdgcn_global_load_lds(                                            \
      (const __attribute__((address_space(1))) void*)(uintptr_t)(gsrc),        \
      (__attribute__((address_space(3))) void*)(uint32_t)(uintptr_t)(ldst),    \
      16, 0, 0)

static __device__ __forceinline__ unsigned short f32_to_bf16_bits(float f) {
  union { float f; uint32_t u; } x; x.f = f;
  uint32_t u = x.u;
  u += 0x7fffu + ((u >> 16) & 1u);   // round-to-nearest-even
  return (unsigned short)(u >> 16);
}

// ---------------------------------------------------------------- converts
__global__ __launch_bounds__(256) void cvt_f32_bf16(
    const float4* __restrict__ in, ushort4* __restrict__ out, int n4) {
  const int stride = gridDim.x * blockDim.x;
  for (int i = blockIdx.x * blockDim.x + threadIdx.x; i < n4; i += stride) {
    float4 v = in[i];
    ushort4 o;
    o.x = f32_to_bf16_bits(v.x);
    o.y = f32_to_bf16_bits(v.y);
    o.z = f32_to_bf16_bits(v.z);
    o.w = f32_to_bf16_bits(v.w);
    out[i] = o;
  }
}

// transpose R x C f32 -> C x R bf16
__global__ __launch_bounds__(256) void transpose_cvt(
    const float* __restrict__ in, unsigned short* __restrict__ out, int R, int C) {
  __shared__ float tile[32][33];
  const int bx = blockIdx.x * 32;
  const int by = blockIdx.y * 32;
  const int tx = threadIdx.x;
  const int ty = threadIdx.y;
#pragma unroll
  for (int j = 0; j < 32; j += 8)
    tile[ty + j][tx] = in[(size_t)(by + ty + j) * C + bx + tx];
  __syncthreads();
#pragma unroll
  for (int j = 0; j < 32; j += 8)
    out[(size_t)(bx + ty + j) * R + by + tx] = f32_to_bf16_bits(tile[tx][ty + j]);
}

// ---------------------------------------------------------------- GEMM
// 256x256 tile, BK=64, 8 waves (2M x 4N), 4 phases/K-tile.
// Register-neutral read skew: av0-next prefetched at P4 (lgkmcnt(8) tolerance),
// av1 prefetched at P2; only bv0 (P1) blocks in-phase. One vmcnt(4)/K-tile.
template <bool OUT_BF16>
__global__ __launch_bounds__(512, 1) void gemm_bt(
    const unsigned short* __restrict__ A,
    const unsigned short* __restrict__ BT,
    unsigned short* __restrict__ Cb,
    float* __restrict__ Cf,
    const float* __restrict__ bias,
    int M, int N) {
  constexpr int K = 2048;
  constexpr int BK = 64;
  constexpr int NKT = K / BK;          // 32
  __shared__ __align__(16) char lds[131072];  // [2 bufs][A 32KB | B 32KB]

  const int nbx = N / 256;
  const int nwg = gridDim.x;           // % 8 == 0
  const int bid = blockIdx.x;
  const int swzb = (bid & 7) * (nwg >> 3) + (bid >> 3);
  const int by = swzb / nbx;
  const int bx = swzb % nbx;

  const int t    = threadIdx.x;
  const int lane = t & 63;
  const int wid  = t >> 6;             // 0..7
  const int wr   = wid >> 2;           // 0..1 (M)
  const int wc   = wid & 3;            // 0..3 (N)
  const int lr   = lane & 15;
  const int g    = lane >> 4;          // 0..3

  const unsigned short* aSrc = A  + (size_t)by * 256 * K;
  const unsigned short* bSrc = BT + (size_t)bx * 256 * K;

  // staging source offsets (inverse-swizzled global, linear LDS dest)
  int aoff[2], boff[2];
#pragma unroll
  for (int i = 0; i < 2; ++i) {
    const int p   = (i * 512 + t) * 16;
    const int lo  = p ^ (((p >> 7) & 7) << 4);
    const int rih = lo >> 7;
    const int kbe = (lo & 127) >> 1;
    aoff[i] = (((rih >> 6) << 7) + (rih & 63)) * K + kbe;
    boff[i] = (((rih >> 5) << 6) + (rih & 31)) * K + kbe;
  }
  const int ldst = wid << 10;

  auto stageA = [&](int h, int k0, char* bufA) {
#pragma unroll
    for (int i = 0; i < 2; ++i)
      GLOAD16(aSrc + aoff[i] + h * (64 * K) + k0, bufA + h * 16384 + i * 8192 + ldst);
  };
  auto stageB = [&](int h, int k0, char* bufB) {
#pragma unroll
    for (int i = 0; i < 2; ++i)
      GLOAD16(bSrc + boff[i] + h * (32 * K) + k0, bufB + h * 16384 + i * 8192 + ldst);
  };

  // swizzled ds_read addresses
  const int sw   = (lr & 7) << 4;
  const int col0 = (g * 16) ^ sw;
  const int col1 = (64 + g * 16) ^ sw;
  const int aRow = (wr * 64 + lr) * 128;
  const int bRow = (wc * 32 + lr) * 128;

  f32x4_t acc[8][4] = {};
  bf16x8_t av0[4][2], av1[4][2];       // A quadrant frags [m2][ks]
  bf16x8_t bv0[2][2], bv1[2][2];       // B pair frags [e][ks]

#define LDA_INTO(dst, bufA_, q)                                                \
  {                                                                            \
    const char* _b = (bufA_) + (q) * 16384 + aRow;                             \
    _Pragma("unroll") for (int m2 = 0; m2 < 4; ++m2) {                         \
      dst[m2][0] = *(const bf16x8_t*)(_b + m2 * 2048 + col0);                  \
      dst[m2][1] = *(const bf16x8_t*)(_b + m2 * 2048 + col1);                  \
    }                                                                          \
  }
#define LDB_INTO(dst, bufB_, pair)                                             \
  {                                                                            \
    _Pragma("unroll") for (int e = 0; e < 2; ++e) {                            \
      const int nf = (pair) * 2 + e;                                           \
      const char* _b = (bufB_) + (nf >> 1) * 16384 + (nf & 1) * 2048 + bRow;   \
      dst[e][0] = *(const bf16x8_t*)(_b + col0);                               \
      dst[e][1] = *(const bf16x8_t*)(_b + col1);                               \
    }                                                                          \
  }
#define MFMAQ(AV, BV, Q, PAIR)                                                 \
  _Pragma("unroll") for (int m2 = 0; m2 < 4; ++m2)                             \
  _Pragma("unroll") for (int e = 0; e < 2; ++e)                                \
  _Pragma("unroll") for (int ks = 0; ks < 2; ++ks)                             \
    acc[(Q) * 4 + m2][(PAIR) * 2 + e] = __builtin_amdgcn_mfma_f32_16x16x32_bf16( \
        AV[m2][ks], BV[e][ks], acc[(Q) * 4 + m2][(PAIR) * 2 + e], 0, 0, 0);

#define SBR __builtin_amdgcn_sched_barrier(0)
  // barrier -> counted lgkm wait -> fence -> boost
#define TAIL(N)                                                                \
  SBR; __builtin_amdgcn_s_barrier();                                           \
  asm volatile("s_waitcnt lgkmcnt(" #N ")" ::: "memory");                      \
  SBR; __builtin_amdgcn_s_setprio(1);
#define PEND                                                                   \
  __builtin_amdgcn_s_setprio(0); SBR; __builtin_amdgcn_s_barrier();

  // ---- prologue: tile0 full + tile1 {Ah0, Bh1}; pre-read av0 of tile0
  {
    char* b0A = lds;
    char* b0B = lds + 32768;
    char* b1A = lds + 65536;
    char* b1B = b1A + 32768;
    stageA(0, 0, b0A); stageA(1, 0, b0A);
    stageB(0, 0, b0B); stageB(1, 0, b0B);
    stageA(0, BK, b1A);
    stageB(1, BK, b1B);
    asm volatile("s_waitcnt vmcnt(4)" ::: "memory");  // tile0 landed
    __builtin_amdgcn_s_barrier();
    LDA_INTO(av0, b0A, 0);
  }

  for (int kt = 0; kt < NKT; ++kt) {
    char* cA = lds + (kt & 1) * 65536;
    char* cB = cA + 32768;
    char* nA = lds + ((kt + 1) & 1) * 65536;
    char* nB = nA + 32768;
    const int k1 = (kt + 1) * BK;
    const int k2 = (kt + 2) * BK;
    const bool s1 = kt + 1 < NKT;
    const bool s2 = kt + 2 < NKT;

    // P1: read bv0(cur); stage (kt+1)Ah1 -> nA; M1 = (q0, p0)
    LDB_INTO(bv0, cB, 0);
    if (s1) stageA(1, k1, nA);
    TAIL(0); MFMAQ(av0, bv0, 0, 0); PEND;

    // P2: read bv1(cur) then av1(cur); stage (kt+1)Bh0 -> nB; M2 = (q0, p1)
    LDB_INTO(bv1, cB, 1);
    LDA_INTO(av1, cA, 1);
    if (s1) stageB(0, k1, nB);
    TAIL(8); MFMAQ(av0, bv1, 0, 1); PEND;   // drains exactly bv1 (FIFO)

    // P3: stage (kt+2)Ah0 -> cA (h0 reads done since prev P4/P1); M3 = (q1, p1)
    if (s2) stageA(0, k2, cA);
    TAIL(0); MFMAQ(av1, bv1, 1, 1); PEND;

    // P4: stage (kt+2)Bh1 -> cB; counted vmcnt; prefetch next av0; M4 = (q1, p0)
    if (s2) stageB(1, k2, cB);
    if (s2) { asm volatile("s_waitcnt vmcnt(4)" ::: "memory"); }
    else    { asm volatile("s_waitcnt vmcnt(0)" ::: "memory"); }
    if (s1) {
      LDA_INTO(av0, nA, 0);   // next tile's q0 — tolerated in flight
      TAIL(8);
    } else {
      TAIL(0);
    }
    MFMAQ(av1, bv0, 1, 0); PEND;
  }

  // ---- epilogue: C/D map col=lane&15, row=(lane>>4)*4+j
  const int rbase = by * 256 + wr * 128 + g * 4;
  const int cbase = bx * 256 + wc * 64 + lr;
#pragma unroll
  for (int m = 0; m < 8; ++m) {
#pragma unroll
    for (int nf = 0; nf < 4; ++nf) {
      const int col = cbase + nf * 16;
#pragma unroll
      for (int j = 0; j < 4; ++j) {
        const size_t off = (size_t)(rbase + (m >> 2) * 64 + (m & 3) * 16 + j) * N + col;
        if constexpr (OUT_BF16) {
          Cb[off] = f32_to_bf16_bits(acc[m][nf][j]);
        } else {
          Cf[off] = acc[m][nf][j] + bias[col];
        }
      }
    }
  }
#undef LDA_INTO
#undef LDB_INTO
#undef MFMAQ
#undef SBR
#undef TAIL
#undef PEND
}

// ---------------------------------------------------------------- attention
__global__ __launch_bounds__(256) void attn_heads(
    const unsigned short* __restrict__ qkv,  // [T][6144] bf16
    unsigned short* __restrict__ attn) {     // [T][2048] bf16
  __shared__ __align__(16) unsigned short sQKV[NQKV];
  __shared__ float sW[16][16];

  const int t = threadIdx.x;
  const size_t qbase = (size_t)blockIdx.x * NQKV;

  const uint4* gp = (const uint4*)(qkv + qbase);
  uint4* l = (uint4*)sQKV;
#pragma unroll
  for (int i = 0; i < 3; ++i) {
    const int idx = i * 256 + t;
    int dst = idx;
    if (idx >= 256 && idx < 512) {
      const int r = (idx - 256) >> 4;
      const int c = idx & 15;
      dst = 256 + r * 16 + (c ^ (r & 7));
    }
    l[dst] = gp[idx];
  }
  __syncthreads();

  const int h = t >> 4;
  const int H = t & 15;
  const bf16x8_t* q8 = (const bf16x8_t*)sQKV + h * 16;
  const bf16x8_t* k8 = (const bf16x8_t*)sQKV + 256;
  float s = 0.f;
#pragma unroll
  for (int d8 = 0; d8 < 16; ++d8) {
    bf16x8_t qv = q8[d8];
    bf16x8_t kv = k8[H * 16 + (d8 ^ (H & 7))];
#pragma unroll
    for (int j = 0; j < 8; ++j)
      s = fmaf((float)qv[j], (float)kv[j], s);
  }
  s *= 0.08838834764831843f;

  float mx = s;
#pragma unroll
  for (int o = 8; o; o >>= 1) mx = fmaxf(mx, __shfl_xor(mx, o));
  const float e = __expf(s - mx);
  float sum = e;
#pragma unroll
  for (int o = 8; o; o >>= 1) sum += __shfl_xor(sum, o);
  sW[h][H] = e / sum;
  __syncthreads();

  const int d0c = t & 15;
  const bf16x8_t* v8 = (const bf16x8_t*)sQKV + 512;
  float accv[8] = {};
#pragma unroll
  for (int j = 0; j < 16; ++j) {
    const float w = sW[h][j];
    const bf16x8_t vv = v8[j * 16 + d0c];
#pragma unroll
    for (int jj = 0; jj < 8; ++jj)
      accv[jj] = fmaf(w, (float)vv[jj], accv[jj]);
  }
  bf16x8_t o;
#pragma unroll
  for (int jj = 0; jj < 8; ++jj) o[jj] = (__bf16)accv[jj];
  *(bf16x8_t*)(attn + (size_t)blockIdx.x * EMB + h * 128 + d0c * 8) = o;
}

// ---------------------------------------------------------------- launch
extern "C" void kernel_launch(void* const* d_in, const int* in_sizes, int n_in,
                              void* d_out, int out_size, void* d_ws, size_t ws_size,
                              hipStream_t stream) {
  const float* x    = (const float*)d_in[0];
  const float* Wqkv = (const float*)d_in[1];
  const float* Wout = (const float*)d_in[2];
  const float* bout = (const float*)d_in[3];
  float* out = (float*)d_out;

  unsigned short* xb    = (unsigned short*)d_ws;          // 33,554,432
  unsigned short* wqkvT = xb    + (size_t)33554432;       // 12,582,912
  unsigned short* woutT = wqkvT + (size_t)12582912;       //  4,194,304
  unsigned short* qkv   = woutT + (size_t)4194304;        // 100,663,296
  unsigned short* attn  = qkv   + (size_t)100663296;      // 33,554,432

  cvt_f32_bf16<<<2048, 256, 0, stream>>>((const float4*)x, (ushort4*)xb, 33554432 / 4);
  transpose_cvt<<<dim3(6144 / 32, 2048 / 32), dim3(32, 8), 0, stream>>>(Wqkv, wqkvT, 2048, 6144);
  transpose_cvt<<<dim3(2048 / 32, 2048 / 32), dim3(32, 8), 0, stream>>>(Wout, woutT, 2048, 2048);
  // qkv = x @ W_qkv : grid 64*24 = 1536 (%8==0)
  gemm_bt<true><<<(16384 / 256) * (6144 / 256), 512, 0, stream>>>(
      xb, wqkvT, qkv, nullptr, nullptr, 16384, 6144);
  attn_heads<<<TOKENS, 256, 0, stream>>>(qkv, attn);
  // out = attn @ W_out + b_out : grid 64*8 = 512 (%8==0)
  gemm_bt<false><<<(16384 / 256) * (2048 / 256), 512, 0, stream>>>(
      attn, woutT, nullptr, out, bout, 16384, 2048);
}